// Round 7
// baseline (1424.823 us; speedup 1.0000x reference)
//
#include <hip/hip_runtime.h>

#define NN    48
#define DD    16
#define HH    256
#define EE    2256
#define BB    32
#define NPRED 8
#define LSTR  56
#define STP   20                     // state LDS row stride (floats)
#define ROWB  80                     // Apl row stride bytes (5x16B, ~2-way banks)
#define TMAX  7                      // packed tiles/block <= 7
#define APL_PLANE (TMAX*16*ROWB)     // 8960 B per plane
#define APL_BUF   (3*APL_PLANE)      // one double-buffer half (3 planes)

typedef __attribute__((ext_vector_type(4))) float f32x4;
typedef __attribute__((ext_vector_type(8))) short short8;

__device__ __forceinline__ float bf2f(unsigned short h) {
    union { unsigned u; float f; } v; v.u = ((unsigned)h) << 16; return v.f;
}
__device__ __forceinline__ unsigned short f2bf(float x) {
    union { float f; unsigned u; } v; v.f = x;
    unsigned r = v.u + 0x7fffu + ((v.u >> 16) & 1u);
    return (unsigned short)(r >> 16);
}

// ---------------------------------------------------------------------------
// Setup: unchanged (verified).
// ---------------------------------------------------------------------------
__global__ __launch_bounds__(256) void k_setup(
    const float* __restrict__ time_segs,
    const float* __restrict__ edge_types,
    const float* __restrict__ W1,      // (2,32,256)
    const float* __restrict__ W2,      // (2,256,256)
    float* __restrict__ state,
    float* __restrict__ W1T,           // (2,256,32)
    unsigned short* __restrict__ W2f,  // 393216
    int* __restrict__ lists,
    int* __restrict__ counts)
{
    const int tid = blockIdx.x * 256 + threadIdx.x;   // 0..1535
    for (int i = tid; i < BB*NN*DD; i += BB*NN)
        state[i] = time_segs[i];
    for (int i = tid; i < 2*HH*32; i += BB*NN) {
        const int t = i >> 13, r = i & 8191, h = r >> 5, f = r & 31;
        W1T[i] = W1[(t*32 + f)*HH + h];
    }
    for (int i = tid; i < 2*8*16*64*8; i += BB*NN) {
        const int j  = i & 7, l = (i >> 3) & 63, nt = (i >> 9) & 15;
        const int kt = (i >> 13) & 7, t = (i >> 16) & 1;
        const int k = kt*32 + ((l >> 4) << 3) + j;
        const int n = nt*16 + (l & 15);
        const float w = W2[((size_t)t*HH + k)*HH + n];
        const unsigned short h0 = f2bf(w);  const float r1 = w  - bf2f(h0);
        const unsigned short h1 = f2bf(r1); const float r2 = r1 - bf2f(h1);
        const unsigned short h2 = f2bf(r2);
        const size_t rest = (size_t)kt*8192 + nt*512 + l*8 + j;
        W2f[(size_t)(t*3+0)*65536 + rest] = h0;
        W2f[(size_t)(t*3+1)*65536 + rest] = h1;
        W2f[(size_t)(t*3+2)*65536 + rest] = h2;
    }
    const int b = tid / NN;
    const int n = tid % NN;
    int* lst = lists + tid * LSTR;
    int c = 0;
    for (int s = 0; s < NN; ++s) {
        if (s == n) continue;
        const int e = s * 47 + (n > s ? n - 1 : n);
        if (edge_types[((size_t)b*EE + e)*3 + 1] > 0.5f) lst[c++] = s;
    }
    const int c1 = c;
    for (int s = 0; s < NN; ++s) {
        if (s == n) continue;
        const int e = s * 47 + (n > s ? n - 1 : n);
        if (edge_types[((size_t)b*EE + e)*3 + 2] > 0.5f) lst[c++] = s;
    }
    counts[tid*2 + 0] = c1;
    counts[tid*2 + 1] = c - c1;
    for (int i = c; i < LSTR; ++i) lst[i] = 0;
}

// ---------------------------------------------------------------------------
// Layer-1 slice for k-tile kt: exact fp32, 1 col/thread, TRUNCATION split
// (a0,a1,a2 reconstruct fp32 exactly: 8+8+8 mantissa bits).
// ---------------------------------------------------------------------------
__device__ __forceinline__ void l1_slice(
    int kt, char* __restrict__ buf,
    int col, int rgrp, int n0, int tAt, int tBt,
    const float* __restrict__ st, const int* __restrict__ rowinfo,
    const float* __restrict__ W1T, const float* __restrict__ b1)
{
    const int col0 = kt*32 + col;
    int secBase = 0;
    #pragma unroll
    for (int t = 0; t < 2; ++t) {
        const int secT = t ? tBt : tAt;
        if (secT) {
            const float* Wc = W1T + ((size_t)t*HH + col0)*32;
            float4 wa[4];
            #pragma unroll
            for (int f4 = 0; f4 < 4; ++f4) wa[f4] = ((const float4*)Wc)[f4];
            float vtA = b1[t*HH + col0], vtB = vtA;
            #pragma unroll
            for (int f4 = 0; f4 < 4; ++f4) {
                const float4 w  = ((const float4*)(Wc + 16))[f4];
                const float4 s0 = *(const float4*)(st + n0*STP + f4*4);
                const float4 s1 = *(const float4*)(st + (n0+1)*STP + f4*4);
                vtA = fmaf(s0.x,w.x, fmaf(s0.y,w.y, fmaf(s0.z,w.z, fmaf(s0.w,w.w, vtA))));
                vtB = fmaf(s1.x,w.x, fmaf(s1.y,w.y, fmaf(s1.z,w.z, fmaf(s1.w,w.w, vtB))));
            }
            const int rend = secBase + secT*16;
            for (int r = secBase + rgrp; r < rend; r += 16) {
                const int info = rowinfo[r];
                const int src  = info & 255;
                float u = (info & 256) ? vtB : vtA;
                const float* srow = st + src*STP;
                #pragma unroll
                for (int f4 = 0; f4 < 4; ++f4) {
                    const float4 s4 = *(const float4*)(srow + f4*4);
                    u = fmaf(s4.x,wa[f4].x, fmaf(s4.y,wa[f4].y, fmaf(s4.z,wa[f4].z, fmaf(s4.w,wa[f4].w, u))));
                }
                u = fmaxf(u, 0.f);
                union { float f; unsigned v; } x, h0, e0, h1, e1;
                x.f = u;
                const unsigned short a0 = (unsigned short)(x.v >> 16);
                h0.v = x.v & 0xffff0000u;
                e0.f = x.f - h0.f;
                const unsigned short a1 = (unsigned short)(e0.v >> 16);
                h1.v = e0.v & 0xffff0000u;
                e1.f = e0.f - h1.f;
                const unsigned short a2 = (unsigned short)(e1.v >> 16);
                char* p = buf + r*ROWB + col*2;
                *(unsigned short*)(p)               = a0;
                *(unsigned short*)(p + APL_PLANE)   = a1;
                *(unsigned short*)(p + 2*APL_PLANE) = a2;
            }
        }
        secBase += secT*16;
    }
}

// ---------------------------------------------------------------------------
// Encoder: 512 threads, block = 2 nodes, edges packed per type.
// Pipelined: per kt {issue B loads -> L1(kt+1) into buf^1 -> MFMA(kt) from
// buf -> barrier}. One barrier per kt; B L2-latency hidden under L1 VALU.
// ---------------------------------------------------------------------------
__global__ __launch_bounds__(512, 2) void k_enc(
    const float* __restrict__ state,
    const int*   __restrict__ lists,
    const int*   __restrict__ counts,
    const float* __restrict__ W1T,   // (2,256,32) fp32
    const float* __restrict__ b1,    // (2,256)
    const unsigned short* __restrict__ W2f,
    const float* __restrict__ b2,    // (2,256)
    float* __restrict__ node_msg)
{
    const int pair = blockIdx.x % (NN/2);
    const int b    = blockIdx.x / (NN/2);
    const int n0   = pair * 2;
    const int tid  = threadIdx.x;        // 0..511
    const int lane = tid & 63, wave = tid >> 6;
    const int col  = tid & 31;
    const int rgrp = tid >> 5;

    __shared__ __align__(16) float st[NN*STP];         // 3.84 KB
    __shared__ __align__(16) char  Apl[2*APL_BUF];     // 53.76 KB (double buf)
    __shared__ int lst_s[2][LSTR];
    __shared__ int rowinfo[TMAX*16];
    __shared__ int cnt_s[4];

    for (int i = tid; i < NN*DD; i += 512)
        st[(i >> 4)*STP + (i & 15)] = state[(size_t)b*NN*DD + i];
    for (int i = tid; i < 2*LSTR; i += 512)
        lst_s[i/LSTR][i%LSTR] = lists[(b*NN + n0 + i/LSTR)*LSTR + (i%LSTR)];
    if (tid < 4) cnt_s[tid] = counts[(b*NN + n0 + (tid>>1))*2 + (tid&1)];
    __syncthreads();

    const int c00 = cnt_s[0], c10 = cnt_s[1], c01 = cnt_s[2], c11 = cnt_s[3];
    const int tA  = c00 + c01, tB = c10 + c11;
    const int tAt = (tA + 15) >> 4, tBt = (tB + 15) >> 4;
    const int tiles = tAt + tBt;

    for (int r = tid; r < tiles*16; r += 512) {
        int g, src;
        if (r < tAt*16) {
            if (r < c00)     { src = lst_s[0][r];            g = 0; }
            else if (r < tA) { src = lst_s[1][r - c00];      g = 1; }
            else             { src = c00 ? lst_s[0][0] : lst_s[1][0]; g = 4; }
        } else {
            const int s = r - tAt*16;
            if (s < c10)     { src = lst_s[0][c00 + s];      g = 2; }
            else if (s < tB) { src = lst_s[1][c01 + s - c10]; g = 3; }
            else             { src = c10 ? lst_s[0][c00] : lst_s[1][c01]; g = 4; }
        }
        rowinfo[r] = src | (g << 8);
    }
    __syncthreads();

    f32x4 acc[TMAX][2];
    #pragma unroll
    for (int q = 0; q < TMAX; ++q) {
        acc[q][0] = (f32x4){0.f, 0.f, 0.f, 0.f};
        acc[q][1] = (f32x4){0.f, 0.f, 0.f, 0.f};
    }

    // prologue: L1 for kt=0 into buffer 0
    l1_slice(0, Apl, col, rgrp, n0, tAt, tBt, st, rowinfo, W1T, b1);
    __syncthreads();

    for (int kt = 0; kt < 8; ++kt) {
        const int cur = kt & 1;
        // ---- issue B loads early (consumed after L1 -> latency hidden) ----
        short8 B1[2][3], B2[2][3];
        if (tAt) {
            #pragma unroll
            for (int i = 0; i < 2; ++i)
                #pragma unroll
                for (int p = 0; p < 3; ++p)
                    B1[i][p] = *(const short8*)(W2f + ((size_t)p*65536
                                 + (size_t)kt*8192 + (wave*2 + i)*512 + lane*8));
        }
        if (tBt) {
            #pragma unroll
            for (int i = 0; i < 2; ++i)
                #pragma unroll
                for (int p = 0; p < 3; ++p)
                    B2[i][p] = *(const short8*)(W2f + ((size_t)(3+p)*65536
                                 + (size_t)kt*8192 + (wave*2 + i)*512 + lane*8));
        }
        // ---- L1 for kt+1 into the other buffer ----
        if (kt < 7)
            l1_slice(kt+1, Apl + (cur^1)*APL_BUF, col, rgrp, n0, tAt, tBt,
                     st, rowinfo, W1T, b1);
        // ---- MFMA for kt from current buffer ----
        const int abase = (lane & 15)*ROWB + (lane >> 4)*16;
        const char* base = Apl + cur*APL_BUF;
        if (tAt) {
            #pragma unroll
            for (int q = 0; q < TMAX; ++q) {
                if (q < tAt) {
                    short8 Af[3];
                    const char* ap = base + q*16*ROWB + abase;
                    #pragma unroll
                    for (int p = 0; p < 3; ++p)
                        Af[p] = *(const short8*)(ap + p*APL_PLANE);
                    #pragma unroll
                    for (int i = 0; i < 2; ++i) {
                        f32x4 a = acc[q][i];
                        a = __builtin_amdgcn_mfma_f32_16x16x32_bf16(Af[2], B1[i][0], a, 0, 0, 0);
                        a = __builtin_amdgcn_mfma_f32_16x16x32_bf16(Af[1], B1[i][1], a, 0, 0, 0);
                        a = __builtin_amdgcn_mfma_f32_16x16x32_bf16(Af[0], B1[i][2], a, 0, 0, 0);
                        a = __builtin_amdgcn_mfma_f32_16x16x32_bf16(Af[1], B1[i][0], a, 0, 0, 0);
                        a = __builtin_amdgcn_mfma_f32_16x16x32_bf16(Af[0], B1[i][1], a, 0, 0, 0);
                        a = __builtin_amdgcn_mfma_f32_16x16x32_bf16(Af[0], B1[i][0], a, 0, 0, 0);
                        acc[q][i] = a;
                    }
                }
            }
        }
        if (tBt) {
            #pragma unroll
            for (int q = 0; q < TMAX; ++q) {
                if (q >= tAt && q < tiles) {
                    short8 Af[3];
                    const char* ap = base + q*16*ROWB + abase;
                    #pragma unroll
                    for (int p = 0; p < 3; ++p)
                        Af[p] = *(const short8*)(ap + p*APL_PLANE);
                    #pragma unroll
                    for (int i = 0; i < 2; ++i) {
                        f32x4 a = acc[q][i];
                        a = __builtin_amdgcn_mfma_f32_16x16x32_bf16(Af[2], B2[i][0], a, 0, 0, 0);
                        a = __builtin_amdgcn_mfma_f32_16x16x32_bf16(Af[1], B2[i][1], a, 0, 0, 0);
                        a = __builtin_amdgcn_mfma_f32_16x16x32_bf16(Af[0], B2[i][2], a, 0, 0, 0);
                        a = __builtin_amdgcn_mfma_f32_16x16x32_bf16(Af[1], B2[i][0], a, 0, 0, 0);
                        a = __builtin_amdgcn_mfma_f32_16x16x32_bf16(Af[0], B2[i][1], a, 0, 0, 0);
                        a = __builtin_amdgcn_mfma_f32_16x16x32_bf16(Af[0], B2[i][0], a, 0, 0, 0);
                        acc[q][i] = a;
                    }
                }
            }
        }
        __syncthreads();
    }

    // ---- readout: relu(acc+b2), per-row node mask, shfl-reduce, store ----
    float b2v[2][2];
    #pragma unroll
    for (int t = 0; t < 2; ++t)
        #pragma unroll
        for (int i = 0; i < 2; ++i)
            b2v[t][i] = b2[t*HH + (wave*2 + i)*16 + (lane & 15)];

    float p0[2], p1[2];
    p0[0] = p0[1] = p1[0] = p1[1] = 0.f;
    #pragma unroll
    for (int q = 0; q < TMAX; ++q) {
        if (q < tiles) {
            const bool secB = (q >= tAt);
            int gv[4];
            #pragma unroll
            for (int rr = 0; rr < 4; ++rr)
                gv[rr] = rowinfo[q*16 + (lane >> 4)*4 + rr] >> 8;
            #pragma unroll
            for (int i = 0; i < 2; ++i) {
                const float bias = secB ? b2v[1][i] : b2v[0][i];
                #pragma unroll
                for (int rr = 0; rr < 4; ++rr) {
                    const float v = fmaxf(acc[q][i][rr] + bias, 0.f);
                    const bool valid = gv[rr] < 4;
                    p0[i] += (valid && !(gv[rr] & 1)) ? v : 0.f;
                    p1[i] += (valid &&  (gv[rr] & 1)) ? v : 0.f;
                }
            }
        }
    }
    #pragma unroll
    for (int i = 0; i < 2; ++i) {
        float v0 = p0[i], v1 = p1[i];
        v0 += __shfl_xor(v0, 16); v0 += __shfl_xor(v0, 32);
        v1 += __shfl_xor(v1, 16); v1 += __shfl_xor(v1, 32);
        if ((lane >> 4) == 0) {
            node_msg[((size_t)(b*NN + n0  ))*HH + (wave*2 + i)*16 + lane] = v0;
            node_msg[((size_t)(b*NN + n0+1))*HH + (wave*2 + i)*16 + lane] = v1;
        }
    }
}

// ---------------------------------------------------------------------------
// Decoder: unchanged (passing, ~12 us/step).
// ---------------------------------------------------------------------------
__global__ __launch_bounds__(128, 3) void k_dec(
    float* __restrict__ state,
    const float* __restrict__ node_msg,
    const float* __restrict__ W1, const float* __restrict__ b1,
    const float* __restrict__ W2, const float* __restrict__ b2,
    const float* __restrict__ W3, const float* __restrict__ b3,
    float* __restrict__ out, int step)
{
    const int b    = blockIdx.x / 12;
    const int row0 = (blockIdx.x % 12) * 4;
    const int c    = threadIdx.x, c2 = c + 128;

    __shared__ float in_s[4][272];
    __shared__ float d1[4][HH];

    for (int i = threadIdx.x; i < 4*272; i += 128) {
        const int m = i / 272, k = i % 272;
        const int r = row0 + m;
        in_s[m][k] = (k < DD)
            ? state[((size_t)b*NN + r)*DD + k]
            : node_msg[((size_t)b*NN + r)*HH + (k - DD)];
    }
    __syncthreads();

    float a0[4], a1[4];
    {
        const float bb0 = b1[c], bb1 = b1[c2];
        #pragma unroll
        for (int m = 0; m < 4; ++m) { a0[m] = bb0; a1[m] = bb1; }
        #pragma unroll 2
        for (int k4 = 0; k4 < 68; ++k4) {
            const float* wr = W1 + (k4*4)*HH;
            const float w00=wr[c],      w01=wr[c2];
            const float w10=wr[HH+c],   w11=wr[HH+c2];
            const float w20=wr[2*HH+c], w21=wr[2*HH+c2];
            const float w30=wr[3*HH+c], w31=wr[3*HH+c2];
            #pragma unroll
            for (int m = 0; m < 4; ++m) {
                const float4 h = *(const float4*)&in_s[m][k4*4];
                a0[m] = fmaf(h.x,w00, fmaf(h.y,w10, fmaf(h.z,w20, fmaf(h.w,w30, a0[m]))));
                a1[m] = fmaf(h.x,w01, fmaf(h.y,w11, fmaf(h.z,w21, fmaf(h.w,w31, a1[m]))));
            }
        }
        #pragma unroll
        for (int m = 0; m < 4; ++m) {
            d1[m][c]  = fmaxf(a0[m], 0.f);
            d1[m][c2] = fmaxf(a1[m], 0.f);
        }
    }
    __syncthreads();
    {
        const float bb0 = b2[c], bb1 = b2[c2];
        #pragma unroll
        for (int m = 0; m < 4; ++m) { a0[m] = bb0; a1[m] = bb1; }
        #pragma unroll 2
        for (int k4 = 0; k4 < 64; ++k4) {
            const float* wr = W2 + (k4*4)*HH;
            const float w00=wr[c],      w01=wr[c2];
            const float w10=wr[HH+c],   w11=wr[HH+c2];
            const float w20=wr[2*HH+c], w21=wr[2*HH+c2];
            const float w30=wr[3*HH+c], w31=wr[3*HH+c2];
            #pragma unroll
            for (int m = 0; m < 4; ++m) {
                const float4 h = *(const float4*)&d1[m][k4*4];
                a0[m] = fmaf(h.x,w00, fmaf(h.y,w10, fmaf(h.z,w20, fmaf(h.w,w30, a0[m]))));
                a1[m] = fmaf(h.x,w01, fmaf(h.y,w11, fmaf(h.z,w21, fmaf(h.w,w31, a1[m]))));
            }
        }
        __syncthreads();
        #pragma unroll
        for (int m = 0; m < 4; ++m) {
            in_s[m][c]  = fmaxf(a0[m], 0.f);
            in_s[m][c2] = fmaxf(a1[m], 0.f);
        }
    }
    __syncthreads();
    if (threadIdx.x < 64) {
        const int m = threadIdx.x >> 4, cc = threadIdx.x & 15;
        float a = b3[cc];
        #pragma unroll 4
        for (int k4 = 0; k4 < 64; ++k4) {
            const float4 h = *(const float4*)&in_s[m][k4*4];
            a += h.x*W3[(k4*4+0)*16+cc] + h.y*W3[(k4*4+1)*16+cc]
               + h.z*W3[(k4*4+2)*16+cc] + h.w*W3[(k4*4+3)*16+cc];
        }
        const int r = row0 + m;
        const float v = state[((size_t)b*NN + r)*DD + cc] + a;
        state[((size_t)b*NN + r)*DD + cc] = v;
        out[(((size_t)b*NPRED + step)*NN + r)*DD + cc] = v;
    }
}

// ---------------------------------------------------------------------------
extern "C" void kernel_launch(void* const* d_in, const int* in_sizes, int n_in,
                              void* d_out, int out_size, void* d_ws, size_t ws_size,
                              hipStream_t stream)
{
    const float* time_segs  = (const float*)d_in[0];
    const float* edge_types = (const float*)d_in[1];
    const float* enc_W1 = (const float*)d_in[4];
    const float* enc_b1 = (const float*)d_in[5];
    const float* enc_W2 = (const float*)d_in[6];
    const float* enc_b2 = (const float*)d_in[7];
    const float* dec_W1 = (const float*)d_in[8];
    const float* dec_b1 = (const float*)d_in[9];
    const float* dec_W2 = (const float*)d_in[10];
    const float* dec_b2 = (const float*)d_in[11];
    const float* out_W  = (const float*)d_in[12];
    const float* out_b  = (const float*)d_in[13];
    float* out = (float*)d_out;

    float* state    = (float*)d_ws;                    // 24576 f
    float* node_msg = state + BB*NN*DD;                // 393216 f
    float* W1T      = node_msg + BB*NN*HH;             // 16384 f
    unsigned short* W2f = (unsigned short*)(W1T + 2*HH*32);   // 393216 us
    int*   lists    = (int*)(W2f + 2*3*65536);         // 86016 i
    int*   counts   = lists + BB*NN*LSTR;              // 3072 i

    k_setup<<<6, 256, 0, stream>>>(time_segs, edge_types, enc_W1, enc_W2,
                                   state, W1T, W2f, lists, counts);
    for (int stp = 0; stp < NPRED; ++stp) {
        k_enc<<<BB*(NN/2), 512, 0, stream>>>(state, lists, counts,
                                             W1T, enc_b1, W2f, enc_b2, node_msg);
        k_dec<<<BB*12, 128, 0, stream>>>(state, node_msg,
                                         dec_W1, dec_b1, dec_W2, dec_b2,
                                         out_W, out_b, out, stp);
    }
}

// Round 8
// 1011.015 us; speedup vs baseline: 1.4093x; 1.4093x over previous
//
#include <hip/hip_runtime.h>

#define NN    48
#define DD    16
#define HH    256
#define EE    2256
#define BB    32
#define NPRED 8
#define LSTR  56
#define ROWB  80                     // Apl row stride bytes (5x16B, ~2-way banks)
#define TMAX  7                      // packed tiles/block <= 7 (tA+tB<=94)
#define APL_PLANE (TMAX*16*ROWB)     // 8960 B per plane
#define APL_BUF   (3*APL_PLANE)      // 26880 B per dbuf half

typedef __attribute__((ext_vector_type(4))) float f32x4;
typedef __attribute__((ext_vector_type(8))) short short8;

__device__ __forceinline__ float bf2f(unsigned short h) {
    union { unsigned u; float f; } v; v.u = ((unsigned)h) << 16; return v.f;
}
__device__ __forceinline__ unsigned short f2bf(float x) {
    union { float f; unsigned u; } v; v.f = x;
    unsigned r = v.u + 0x7fffu + ((v.u >> 16) & 1u);
    return (unsigned short)(r >> 16);
}

// ---------------------------------------------------------------------------
// Setup: state copy, W1 transpose (for k_dec's fused PQ), W2 bf16x3 split in
// MFMA B-frag order, type-grouped edge lists, and PQ0 tables from time_segs:
//   PQ[nb*1024 + t*512 + pq*256 + c],  P(pq=0)=st.W1src, Q(pq=1)=st.W1tgt+b1
// ---------------------------------------------------------------------------
__global__ __launch_bounds__(256) void k_setup(
    const float* __restrict__ time_segs,
    const float* __restrict__ edge_types,
    const float* __restrict__ W1,      // (2,32,256)
    const float* __restrict__ W2,      // (2,256,256)
    const float* __restrict__ b1,      // (2,256)
    float* __restrict__ state,
    float* __restrict__ W1T,           // (2,256,32)
    unsigned short* __restrict__ W2f,  // 393216
    float* __restrict__ PQ,            // 1572864
    int* __restrict__ lists,
    int* __restrict__ counts)
{
    const int tid = blockIdx.x * 256 + threadIdx.x;   // 0..6143
    const int NT = 24*256;
    for (int i = tid; i < BB*NN*DD; i += NT)
        state[i] = time_segs[i];
    for (int i = tid; i < 2*HH*32; i += NT) {
        const int t = i >> 13, r = i & 8191, h = r >> 5, f = r & 31;
        W1T[i] = W1[(t*32 + f)*HH + h];
    }
    for (int i = tid; i < 2*8*16*64*8; i += NT) {
        const int j  = i & 7, l = (i >> 3) & 63, nt = (i >> 9) & 15;
        const int kt = (i >> 13) & 7, t = (i >> 16) & 1;
        const int k = kt*32 + ((l >> 4) << 3) + j;
        const int n = nt*16 + (l & 15);
        const float w = W2[((size_t)t*HH + k)*HH + n];
        const unsigned short h0 = f2bf(w);  const float r1 = w  - bf2f(h0);
        const unsigned short h1 = f2bf(r1); const float r2 = r1 - bf2f(h1);
        const unsigned short h2 = f2bf(r2);
        const size_t rest = (size_t)kt*8192 + nt*512 + l*8 + j;
        W2f[(size_t)(t*3+0)*65536 + rest] = h0;
        W2f[(size_t)(t*3+1)*65536 + rest] = h1;
        W2f[(size_t)(t*3+2)*65536 + rest] = h2;
    }
    // PQ0 from time_segs (== initial state)
    for (int i = tid; i < BB*NN*1024; i += NT) {
        const int c  = i & 255;
        const int pq = (i >> 8) & 1;
        const int t  = (i >> 9) & 1;
        const int nb = i >> 10;
        float v = pq ? b1[t*HH + c] : 0.f;
        #pragma unroll
        for (int f = 0; f < DD; ++f)
            v = fmaf(time_segs[nb*DD + f], W1[(t*32 + pq*16 + f)*HH + c], v);
        PQ[i] = v;
    }
    if (tid < BB*NN) {
        const int b = tid / NN;
        const int n = tid % NN;
        int* lst = lists + tid * LSTR;
        int c = 0;
        for (int s = 0; s < NN; ++s) {
            if (s == n) continue;
            const int e = s * 47 + (n > s ? n - 1 : n);
            if (edge_types[((size_t)b*EE + e)*3 + 1] > 0.5f) lst[c++] = s;
        }
        const int c1 = c;
        for (int s = 0; s < NN; ++s) {
            if (s == n) continue;
            const int e = s * 47 + (n > s ? n - 1 : n);
            if (edge_types[((size_t)b*EE + e)*3 + 2] > 0.5f) lst[c++] = s;
        }
        counts[tid*2 + 0] = c1;
        counts[tid*2 + 1] = c - c1;
        for (int i = c; i < LSTR; ++i) lst[i] = 0;
    }
}

// ---------------------------------------------------------------------------
// Encoder: 256 threads (4 waves), block = 2 nodes, edges packed per type.
// A-build: h1 = relu(P[src]+Q[tgt]) per col-pair, trunc-split to 3 bf16
// planes in dbuf LDS. MFMA: each wave owns 4 n-tiles; bf16x3 (6 products).
// One barrier per kt.
// ---------------------------------------------------------------------------
__global__ __launch_bounds__(256, 2) void k_enc(
    const int*   __restrict__ lists,
    const int*   __restrict__ counts,
    const float* __restrict__ PQ,
    const unsigned short* __restrict__ W2f,
    const float* __restrict__ b2,    // (2,256)
    float* __restrict__ node_msg)
{
    const int pair = blockIdx.x % (NN/2);
    const int b    = blockIdx.x / (NN/2);
    const int n0   = pair * 2;
    const int tid  = threadIdx.x;        // 0..255
    const int lane = tid & 63, wave = tid >> 6;
    const int cp   = tid & 15;           // col-pair 0..15 within 32-slice
    const int rg   = tid >> 4;           // row 0..15

    __shared__ __align__(16) char Apl[2*APL_BUF];   // 53.76 KB
    __shared__ int lst_s[2][LSTR];
    __shared__ int rowinfo[TMAX*16];                // src | g<<8 (g=t*2+nd, 4=pad)
    __shared__ int cnt_s[4];

    for (int i = tid; i < 2*LSTR; i += 256)
        lst_s[i/LSTR][i%LSTR] = lists[(b*NN + n0 + i/LSTR)*LSTR + (i%LSTR)];
    if (tid < 4) cnt_s[tid] = counts[(b*NN + n0 + (tid>>1))*2 + (tid&1)];
    __syncthreads();

    const int c00 = cnt_s[0], c10 = cnt_s[1], c01 = cnt_s[2], c11 = cnt_s[3];
    const int tA  = c00 + c01, tB = c10 + c11;
    const int tAt = (tA + 15) >> 4, tBt = (tB + 15) >> 4;
    const int tiles = tAt + tBt;
    const int rows  = tiles*16;

    for (int r = tid; r < rows; r += 256) {
        int g, src;
        if (r < tAt*16) {
            if (r < c00)     { src = lst_s[0][r];            g = 0; }
            else if (r < tA) { src = lst_s[1][r - c00];      g = 1; }
            else             { src = c00 ? lst_s[0][0] : lst_s[1][0]; g = 4; }
        } else {
            const int s = r - tAt*16;
            if (s < c10)     { src = lst_s[0][c00 + s];      g = 2; }
            else if (s < tB) { src = lst_s[1][c01 + s - c10]; g = 3; }
            else             { src = c10 ? lst_s[0][c00] : lst_s[1][c01]; g = 4; }
        }
        rowinfo[r] = src | (g << 8);
    }
    __syncthreads();

    f32x4 acc[TMAX][4];
    #pragma unroll
    for (int q = 0; q < TMAX; ++q)
        #pragma unroll
        for (int i = 0; i < 4; ++i)
            acc[q][i] = (f32x4){0.f, 0.f, 0.f, 0.f};

    const float* PQb = PQ + (size_t)b*NN*1024;

    // A-build for k-tile kt into buf
    auto build = [&](int kt, char* buf) {
        const int col0 = kt*32 + cp*2;
        for (int r = rg; r < rows; r += 16) {
            const int info = rowinfo[r];
            const int src  = info & 255;
            const int nd   = (info >> 8) & 1;
            const int t    = (r < tAt*16) ? 0 : 1;
            const float2 Pv = *(const float2*)(PQb + src*1024      + t*512 +       col0);
            const float2 Qv = *(const float2*)(PQb + (n0+nd)*1024  + t*512 + 256 + col0);
            const float u0 = fmaxf(Pv.x + Qv.x, 0.f);
            const float u1 = fmaxf(Pv.y + Qv.y, 0.f);
            union F { float f; unsigned u; };
            F x0, x1; x0.f = u0; x1.f = u1;
            const unsigned d0 = (x0.u >> 16) | (x1.u & 0xffff0000u);
            F h0a, h0b; h0a.u = x0.u & 0xffff0000u; h0b.u = x1.u & 0xffff0000u;
            F e0a, e0b; e0a.f = u0 - h0a.f; e0b.f = u1 - h0b.f;
            const unsigned d1 = (e0a.u >> 16) | (e0b.u & 0xffff0000u);
            F h1a, h1b; h1a.u = e0a.u & 0xffff0000u; h1b.u = e0b.u & 0xffff0000u;
            F e1a, e1b; e1a.f = e0a.f - h1a.f; e1b.f = e0b.f - h1b.f;
            const unsigned d2 = (e1a.u >> 16) | (e1b.u & 0xffff0000u);
            char* p = buf + r*ROWB + cp*4;
            *(unsigned*)(p)               = d0;
            *(unsigned*)(p + APL_PLANE)   = d1;
            *(unsigned*)(p + 2*APL_PLANE) = d2;
        }
    };

    build(0, Apl);
    __syncthreads();

    const int abase = (lane & 15)*ROWB + (lane >> 4)*16;

    for (int kt = 0; kt < 8; ++kt) {
        const int cur = kt & 1;
        const char* bufc = Apl + cur*APL_BUF;
        // B type-0 loads issued early (hidden under A-build VALU)
        short8 BfA[4][3];
        if (tAt) {
            #pragma unroll
            for (int i = 0; i < 4; ++i)
                #pragma unroll
                for (int p = 0; p < 3; ++p)
                    BfA[i][p] = *(const short8*)(W2f + ((size_t)p*65536
                                 + (size_t)kt*8192 + (wave*4 + i)*512 + lane*8));
        }
        if (kt < 7) build(kt+1, Apl + (cur^1)*APL_BUF);
        if (tAt) {
            #pragma unroll
            for (int q = 0; q < TMAX; ++q) {
                if (q < tAt) {
                    short8 Af[3];
                    const char* ap = bufc + q*16*ROWB + abase;
                    #pragma unroll
                    for (int p = 0; p < 3; ++p)
                        Af[p] = *(const short8*)(ap + p*APL_PLANE);
                    #pragma unroll
                    for (int i = 0; i < 4; ++i) {
                        f32x4 a = acc[q][i];
                        a = __builtin_amdgcn_mfma_f32_16x16x32_bf16(Af[2], BfA[i][0], a, 0, 0, 0);
                        a = __builtin_amdgcn_mfma_f32_16x16x32_bf16(Af[1], BfA[i][1], a, 0, 0, 0);
                        a = __builtin_amdgcn_mfma_f32_16x16x32_bf16(Af[0], BfA[i][2], a, 0, 0, 0);
                        a = __builtin_amdgcn_mfma_f32_16x16x32_bf16(Af[1], BfA[i][0], a, 0, 0, 0);
                        a = __builtin_amdgcn_mfma_f32_16x16x32_bf16(Af[0], BfA[i][1], a, 0, 0, 0);
                        a = __builtin_amdgcn_mfma_f32_16x16x32_bf16(Af[0], BfA[i][0], a, 0, 0, 0);
                        acc[q][i] = a;
                    }
                }
            }
        }
        if (tBt) {
            short8 BfB[4][3];
            #pragma unroll
            for (int i = 0; i < 4; ++i)
                #pragma unroll
                for (int p = 0; p < 3; ++p)
                    BfB[i][p] = *(const short8*)(W2f + ((size_t)(3+p)*65536
                                 + (size_t)kt*8192 + (wave*4 + i)*512 + lane*8));
            #pragma unroll
            for (int q = 0; q < TMAX; ++q) {
                if (q >= tAt && q < tiles) {
                    short8 Af[3];
                    const char* ap = bufc + q*16*ROWB + abase;
                    #pragma unroll
                    for (int p = 0; p < 3; ++p)
                        Af[p] = *(const short8*)(ap + p*APL_PLANE);
                    #pragma unroll
                    for (int i = 0; i < 4; ++i) {
                        f32x4 a = acc[q][i];
                        a = __builtin_amdgcn_mfma_f32_16x16x32_bf16(Af[2], BfB[i][0], a, 0, 0, 0);
                        a = __builtin_amdgcn_mfma_f32_16x16x32_bf16(Af[1], BfB[i][1], a, 0, 0, 0);
                        a = __builtin_amdgcn_mfma_f32_16x16x32_bf16(Af[0], BfB[i][2], a, 0, 0, 0);
                        a = __builtin_amdgcn_mfma_f32_16x16x32_bf16(Af[1], BfB[i][0], a, 0, 0, 0);
                        a = __builtin_amdgcn_mfma_f32_16x16x32_bf16(Af[0], BfB[i][1], a, 0, 0, 0);
                        a = __builtin_amdgcn_mfma_f32_16x16x32_bf16(Af[0], BfB[i][0], a, 0, 0, 0);
                        acc[q][i] = a;
                    }
                }
            }
        }
        __syncthreads();
    }

    // ---- readout: relu(acc+b2), per-row node mask, shfl-reduce, store ----
    float b2v[2][4];
    #pragma unroll
    for (int t = 0; t < 2; ++t)
        #pragma unroll
        for (int i = 0; i < 4; ++i)
            b2v[t][i] = b2[t*HH + (wave*4 + i)*16 + (lane & 15)];

    float p0[4], p1[4];
    #pragma unroll
    for (int i = 0; i < 4; ++i) { p0[i] = 0.f; p1[i] = 0.f; }
    #pragma unroll
    for (int q = 0; q < TMAX; ++q) {
        if (q < tiles) {
            const bool secB = (q >= tAt);
            int gv[4];
            #pragma unroll
            for (int rr = 0; rr < 4; ++rr)
                gv[rr] = rowinfo[q*16 + (lane >> 4)*4 + rr] >> 8;
            #pragma unroll
            for (int i = 0; i < 4; ++i) {
                const float bias = secB ? b2v[1][i] : b2v[0][i];
                #pragma unroll
                for (int rr = 0; rr < 4; ++rr) {
                    const float v = fmaxf(acc[q][i][rr] + bias, 0.f);
                    const bool valid = gv[rr] < 4;
                    p0[i] += (valid && !(gv[rr] & 1)) ? v : 0.f;
                    p1[i] += (valid &&  (gv[rr] & 1)) ? v : 0.f;
                }
            }
        }
    }
    #pragma unroll
    for (int i = 0; i < 4; ++i) {
        float v0 = p0[i], v1 = p1[i];
        v0 += __shfl_xor(v0, 16); v0 += __shfl_xor(v0, 32);
        v1 += __shfl_xor(v1, 16); v1 += __shfl_xor(v1, 32);
        if ((lane >> 4) == 0) {
            node_msg[((size_t)(b*NN + n0  ))*HH + (wave*4 + i)*16 + lane] = v0;
            node_msg[((size_t)(b*NN + n0+1))*HH + (wave*4 + i)*16 + lane] = v1;
        }
    }
}

// ---------------------------------------------------------------------------
// Decoder: 256 threads, 4 rows/block. Fused 272->256->256->16 + residual,
// THEN produces the next step's P/Q tables for its 4 nodes (K=16 GEMM).
// ---------------------------------------------------------------------------
__global__ __launch_bounds__(256, 2) void k_dec(
    float* __restrict__ state,
    const float* __restrict__ node_msg,
    const float* __restrict__ W1, const float* __restrict__ b1,   // (272,256)
    const float* __restrict__ W2, const float* __restrict__ b2,   // (256,256)
    const float* __restrict__ W3, const float* __restrict__ b3,   // (256,16)
    const float* __restrict__ eW1T,  // (2,256,32) encoder W1 transposed
    const float* __restrict__ eb1,   // (2,256)
    float* __restrict__ PQ,
    float* __restrict__ out, int step)
{
    const int b    = blockIdx.x / 12;
    const int row0 = (blockIdx.x % 12) * 4;
    const int c    = threadIdx.x;    // 0..255

    __shared__ float in_s[4][272];
    __shared__ float d1s[4][HH];
    __shared__ float stn[4][DD];

    for (int i = c; i < 4*272; i += 256) {
        const int m = i / 272, k = i % 272;
        const int r = row0 + m;
        in_s[m][k] = (k < DD)
            ? state[((size_t)b*NN + r)*DD + k]
            : node_msg[((size_t)b*NN + r)*HH + (k - DD)];
    }
    __syncthreads();

    float a0[4];
    // ---- L1: 272 -> 256, relu ----
    {
        const float bb = b1[c];
        #pragma unroll
        for (int m = 0; m < 4; ++m) a0[m] = bb;
        #pragma unroll 2
        for (int k4 = 0; k4 < 68; ++k4) {
            const float* wr = W1 + (k4*4)*HH;
            const float w0=wr[c], w1_=wr[HH+c], w2_=wr[2*HH+c], w3=wr[3*HH+c];
            #pragma unroll
            for (int m = 0; m < 4; ++m) {
                const float4 h = *(const float4*)&in_s[m][k4*4];
                a0[m] = fmaf(h.x,w0, fmaf(h.y,w1_, fmaf(h.z,w2_, fmaf(h.w,w3, a0[m]))));
            }
        }
        #pragma unroll
        for (int m = 0; m < 4; ++m) d1s[m][c] = fmaxf(a0[m], 0.f);
    }
    __syncthreads();
    // ---- L2: 256 -> 256, relu; overwrite in_s ----
    {
        const float bb = b2[c];
        #pragma unroll
        for (int m = 0; m < 4; ++m) a0[m] = bb;
        #pragma unroll 2
        for (int k4 = 0; k4 < 64; ++k4) {
            const float* wr = W2 + (k4*4)*HH;
            const float w0=wr[c], w1_=wr[HH+c], w2_=wr[2*HH+c], w3=wr[3*HH+c];
            #pragma unroll
            for (int m = 0; m < 4; ++m) {
                const float4 h = *(const float4*)&d1s[m][k4*4];
                a0[m] = fmaf(h.x,w0, fmaf(h.y,w1_, fmaf(h.z,w2_, fmaf(h.w,w3, a0[m]))));
            }
        }
        __syncthreads();
        #pragma unroll
        for (int m = 0; m < 4; ++m) in_s[m][c] = fmaxf(a0[m], 0.f);
    }
    __syncthreads();
    // ---- L3: 256 -> 16, residual, write state + out + stn ----
    if (c < 64) {
        const int m = c >> 4, cc = c & 15;
        float a = b3[cc];
        #pragma unroll 4
        for (int k4 = 0; k4 < 64; ++k4) {
            const float4 h = *(const float4*)&in_s[m][k4*4];
            a += h.x*W3[(k4*4+0)*16+cc] + h.y*W3[(k4*4+1)*16+cc]
               + h.z*W3[(k4*4+2)*16+cc] + h.w*W3[(k4*4+3)*16+cc];
        }
        const int r = row0 + m;
        const float v = state[((size_t)b*NN + r)*DD + cc] + a;
        state[((size_t)b*NN + r)*DD + cc] = v;
        out[(((size_t)b*NPRED + step)*NN + r)*DD + cc] = v;
        stn[m][cc] = v;
    }
    __syncthreads();
    // ---- fused PQ production for next step (4 nodes x 1024 each) ----
    float4 sm[4][4];
    #pragma unroll
    for (int m = 0; m < 4; ++m)
        #pragma unroll
        for (int f4 = 0; f4 < 4; ++f4)
            sm[m][f4] = *(const float4*)&stn[m][f4*4];
    #pragma unroll
    for (int k = 0; k < 4; ++k) {
        const int combo = c + 256*k;           // 0..1023
        const int cc = combo & 255;
        const int pq = (combo >> 8) & 1;
        const int t  = combo >> 9;
        const float* wc = eW1T + ((size_t)t*HH + cc)*32 + pq*16;
        float4 w[4];
        #pragma unroll
        for (int f4 = 0; f4 < 4; ++f4) w[f4] = ((const float4*)wc)[f4];
        const float bias = pq ? eb1[t*HH + cc] : 0.f;
        #pragma unroll
        for (int m = 0; m < 4; ++m) {
            float v = bias;
            #pragma unroll
            for (int f4 = 0; f4 < 4; ++f4) {
                const float4 s = sm[m][f4];
                v = fmaf(s.x,w[f4].x, fmaf(s.y,w[f4].y, fmaf(s.z,w[f4].z, fmaf(s.w,w[f4].w, v))));
            }
            PQ[(size_t)(b*NN + row0 + m)*1024 + t*512 + pq*256 + cc] = v;
        }
    }
}

// ---------------------------------------------------------------------------
extern "C" void kernel_launch(void* const* d_in, const int* in_sizes, int n_in,
                              void* d_out, int out_size, void* d_ws, size_t ws_size,
                              hipStream_t stream)
{
    const float* time_segs  = (const float*)d_in[0];
    const float* edge_types = (const float*)d_in[1];
    const float* enc_W1 = (const float*)d_in[4];
    const float* enc_b1 = (const float*)d_in[5];
    const float* enc_W2 = (const float*)d_in[6];
    const float* enc_b2 = (const float*)d_in[7];
    const float* dec_W1 = (const float*)d_in[8];
    const float* dec_b1 = (const float*)d_in[9];
    const float* dec_W2 = (const float*)d_in[10];
    const float* dec_b2 = (const float*)d_in[11];
    const float* out_W  = (const float*)d_in[12];
    const float* out_b  = (const float*)d_in[13];
    float* out = (float*)d_out;

    // workspace layout (~9.2 MB)
    float* state    = (float*)d_ws;                    // 24576 f
    float* node_msg = state + BB*NN*DD;                // 393216 f
    float* W1T      = node_msg + BB*NN*HH;             // 16384 f
    unsigned short* W2f = (unsigned short*)(W1T + 2*HH*32);   // 393216 us
    int*   lists    = (int*)(W2f + 2*3*65536);         // 86016 i
    int*   counts   = lists + BB*NN*LSTR;              // 3072 i
    float* PQ       = (float*)(counts + BB*NN*2);      // 1572864 f

    k_setup<<<24, 256, 0, stream>>>(time_segs, edge_types, enc_W1, enc_W2,
                                    enc_b1, state, W1T, W2f, PQ, lists, counts);
    for (int stp = 0; stp < NPRED; ++stp) {
        k_enc<<<BB*(NN/2), 256, 0, stream>>>(lists, counts, PQ, W2f,
                                             enc_b2, node_msg);
        k_dec<<<BB*12, 256, 0, stream>>>(state, node_msg,
                                         dec_W1, dec_b1, dec_W2, dec_b2,
                                         out_W, out_b, W1T, enc_b1, PQ, out, stp);
    }
}

// Round 10
// 965.528 us; speedup vs baseline: 1.4757x; 1.0471x over previous
//
#include <hip/hip_runtime.h>

#define NN    48
#define DD    16
#define HH    256
#define EE    2256
#define BB    32
#define NPRED 8
#define LSTR  56
#define TMAX  7                      // packed tiles/block <= 7 (tA+tB<=94)

typedef __attribute__((ext_vector_type(4))) float f32x4;
typedef __attribute__((ext_vector_type(8))) short short8;

__device__ __forceinline__ float bf2f(unsigned short h) {
    union { unsigned u; float f; } v; v.u = ((unsigned)h) << 16; return v.f;
}
__device__ __forceinline__ unsigned short f2bf(float x) {
    union { float f; unsigned u; } v; v.f = x;
    unsigned r = v.u + 0x7fffu + ((v.u >> 16) & 1u);
    return (unsigned short)(r >> 16);
}
// trunc-split two h1 values (even/odd col) into 3 packed bf16 dwords
struct Split3 { unsigned d0, d1, d2; };
__device__ __forceinline__ Split3 split2(float u0, float u1)
{
    union F { float f; unsigned u; };
    Split3 o;
    F x0, x1; x0.f = u0; x1.f = u1;
    o.d0 = (x0.u >> 16) | (x1.u & 0xffff0000u);
    F h0a, h0b; h0a.u = x0.u & 0xffff0000u; h0b.u = x1.u & 0xffff0000u;
    F e0a, e0b; e0a.f = u0 - h0a.f; e0b.f = u1 - h0b.f;
    o.d1 = (e0a.u >> 16) | (e0b.u & 0xffff0000u);
    F h1a, h1b; h1a.u = e0a.u & 0xffff0000u; h1b.u = e0b.u & 0xffff0000u;
    F e1a, e1b; e1a.f = e0a.f - h1a.f; e1b.f = e0b.f - h1b.f;
    o.d2 = (e1a.u >> 16) | (e1b.u & 0xffff0000u);
    return o;
}
union PackA { unsigned u[4]; short8 s; };

// ---------------------------------------------------------------------------
// Setup (192 blocks — R8's 24-block version was latency-bound at 165 us).
// ---------------------------------------------------------------------------
__global__ __launch_bounds__(256) void k_setup(
    const float* __restrict__ time_segs,
    const float* __restrict__ edge_types,
    const float* __restrict__ W1,      // (2,32,256)
    const float* __restrict__ W2,      // (2,256,256)
    const float* __restrict__ b1,      // (2,256)
    float* __restrict__ state,
    float* __restrict__ W1T,           // (2,256,32)
    unsigned short* __restrict__ W2f,  // 393216
    float* __restrict__ PQ,            // 1572864
    int* __restrict__ lists,
    int* __restrict__ counts)
{
    const int tid = blockIdx.x * 256 + threadIdx.x;   // 0..49151
    const int NT = 192*256;
    for (int i = tid; i < BB*NN*DD; i += NT)
        state[i] = time_segs[i];
    for (int i = tid; i < 2*HH*32; i += NT) {
        const int t = i >> 13, r = i & 8191, h = r >> 5, f = r & 31;
        W1T[i] = W1[(t*32 + f)*HH + h];
    }
    for (int i = tid; i < 2*8*16*64*8; i += NT) {
        const int j  = i & 7, l = (i >> 3) & 63, nt = (i >> 9) & 15;
        const int kt = (i >> 13) & 7, t = (i >> 16) & 1;
        const int k = kt*32 + ((l >> 4) << 3) + j;
        const int n = nt*16 + (l & 15);
        const float w = W2[((size_t)t*HH + k)*HH + n];
        const unsigned short h0 = f2bf(w);  const float r1 = w  - bf2f(h0);
        const unsigned short h1 = f2bf(r1); const float r2 = r1 - bf2f(h1);
        const unsigned short h2 = f2bf(r2);
        const size_t rest = (size_t)kt*8192 + nt*512 + l*8 + j;
        W2f[(size_t)(t*3+0)*65536 + rest] = h0;
        W2f[(size_t)(t*3+1)*65536 + rest] = h1;
        W2f[(size_t)(t*3+2)*65536 + rest] = h2;
    }
    for (int i = tid; i < BB*NN*1024; i += NT) {
        const int c  = i & 255;
        const int pq = (i >> 8) & 1;
        const int t  = (i >> 9) & 1;
        const int nb = i >> 10;
        float v = pq ? b1[t*HH + c] : 0.f;
        #pragma unroll
        for (int f = 0; f < DD; ++f)
            v = fmaf(time_segs[nb*DD + f], W1[(t*32 + pq*16 + f)*HH + c], v);
        PQ[i] = v;
    }
    if (tid < BB*NN) {
        const int b = tid / NN;
        const int n = tid % NN;
        int* lst = lists + tid * LSTR;
        int c = 0;
        for (int s = 0; s < NN; ++s) {
            if (s == n) continue;
            const int e = s * 47 + (n > s ? n - 1 : n);
            if (edge_types[((size_t)b*EE + e)*3 + 1] > 0.5f) lst[c++] = s;
        }
        const int c1 = c;
        for (int s = 0; s < NN; ++s) {
            if (s == n) continue;
            const int e = s * 47 + (n > s ? n - 1 : n);
            if (edge_types[((size_t)b*EE + e)*3 + 2] > 0.5f) lst[c++] = s;
        }
        counts[tid*2 + 0] = c1;
        counts[tid*2 + 1] = c - c1;
        for (int i = c; i < LSTR; ++i) lst[i] = 0;
    }
}

// ---------------------------------------------------------------------------
// Encoder v3: register-direct A-fragments, NO LDS staging, NO barriers in
// the k-loop. Each lane builds its own A-frag: h1[row][cols] =
// relu(P[src]+Q[tgt]) for row = q*16+(lane&15), cols = kt*32+(lane>>4)*8+j,
// trunc-split to 3 bf16 planes in registers. bf16x3 MFMA (6 products).
// ---------------------------------------------------------------------------
__global__ __launch_bounds__(256, 2) void k_enc(
    const int*   __restrict__ lists,
    const int*   __restrict__ counts,
    const float* __restrict__ PQ,
    const unsigned short* __restrict__ W2f,
    const float* __restrict__ b2,    // (2,256)
    float* __restrict__ node_msg)
{
    const int pair = blockIdx.x % (NN/2);
    const int b    = blockIdx.x / (NN/2);
    const int n0   = pair * 2;
    const int tid  = threadIdx.x;        // 0..255
    const int lane = tid & 63, wave = tid >> 6;
    const int c8   = (lane >> 4) * 8;    // k-col group within 32-slice

    __shared__ int lst_s[2][LSTR];
    __shared__ int rowinfo[TMAX*16];     // src | g<<8 (g=t*2+nd, 4=pad)
    __shared__ int cnt_s[4];

    for (int i = tid; i < 2*LSTR; i += 256)
        lst_s[i/LSTR][i%LSTR] = lists[(b*NN + n0 + i/LSTR)*LSTR + (i%LSTR)];
    if (tid < 4) cnt_s[tid] = counts[(b*NN + n0 + (tid>>1))*2 + (tid&1)];
    __syncthreads();

    const int c00 = cnt_s[0], c10 = cnt_s[1], c01 = cnt_s[2], c11 = cnt_s[3];
    const int tA  = c00 + c01, tB = c10 + c11;
    const int tAt = (tA + 15) >> 4, tBt = (tB + 15) >> 4;
    const int tiles = tAt + tBt;

    if (tid < TMAX*16) {                 // fill ALL slots (pads -> src 0, g=4)
        const int r = tid;
        int g = 4, src = 0;
        if (r < tAt*16) {
            if (r < c00)     { src = lst_s[0][r];       g = 0; }
            else if (r < tA) { src = lst_s[1][r - c00]; g = 1; }
        } else if (r < tiles*16) {
            const int s = r - tAt*16;
            if (s < c10)     { src = lst_s[0][c00 + s];       g = 2; }
            else if (s < tB) { src = lst_s[1][c01 + s - c10]; g = 3; }
        }
        rowinfo[r] = src | (g << 8);
    }
    __syncthreads();

    // per-lane build metadata (row = lane&15 within each tile)
    int bsrc[TMAX], bnd[TMAX];
    #pragma unroll
    for (int q = 0; q < TMAX; ++q) {
        const int info = rowinfo[q*16 + (lane & 15)];
        bsrc[q] = info & 255;
        bnd[q]  = (info >> 8) & 1;
    }

    f32x4 acc[TMAX][4];
    #pragma unroll
    for (int q = 0; q < TMAX; ++q)
        #pragma unroll
        for (int i = 0; i < 4; ++i)
            acc[q][i] = (f32x4){0.f, 0.f, 0.f, 0.f};

    const float* PQb = PQ + (size_t)b*NN*1024;

    #pragma unroll 1
    for (int kt = 0; kt < 8; ++kt) {
        const int kc = kt*32 + c8;
        #pragma unroll
        for (int t = 0; t < 2; ++t) {
            const int qlo = t ? tAt : 0;
            const int qhi = t ? tiles : tAt;
            if (qlo == qhi) continue;
            // B fragments for this wave's 4 n-tiles
            short8 Bf[4][3];
            #pragma unroll
            for (int i = 0; i < 4; ++i)
                #pragma unroll
                for (int p = 0; p < 3; ++p)
                    Bf[i][p] = *(const short8*)(W2f + ((size_t)(t*3+p)*65536
                                 + (size_t)kt*8192 + (wave*4 + i)*512 + lane*8));
            // Q rows for both nodes at this lane's col group
            const float* qp = PQb + n0*1024 + t*512 + 256 + kc;
            const float4 Q0a = *(const float4*)qp,        Q0b = *(const float4*)(qp+4);
            const float4 Q1a = *(const float4*)(qp+1024), Q1b = *(const float4*)(qp+1028);
            #pragma unroll
            for (int q = 0; q < TMAX; ++q) {
                if (q >= qlo && q < qhi) {
                    const float* pr = PQb + bsrc[q]*1024 + t*512 + kc;
                    const float4 Pa = *(const float4*)pr, Pb = *(const float4*)(pr+4);
                    const int nd = bnd[q];
                    const float u0 = fmaxf(Pa.x + (nd ? Q1a.x : Q0a.x), 0.f);
                    const float u1 = fmaxf(Pa.y + (nd ? Q1a.y : Q0a.y), 0.f);
                    const float u2 = fmaxf(Pa.z + (nd ? Q1a.z : Q0a.z), 0.f);
                    const float u3 = fmaxf(Pa.w + (nd ? Q1a.w : Q0a.w), 0.f);
                    const float u4 = fmaxf(Pb.x + (nd ? Q1b.x : Q0b.x), 0.f);
                    const float u5 = fmaxf(Pb.y + (nd ? Q1b.y : Q0b.y), 0.f);
                    const float u6 = fmaxf(Pb.z + (nd ? Q1b.z : Q0b.z), 0.f);
                    const float u7 = fmaxf(Pb.w + (nd ? Q1b.w : Q0b.w), 0.f);
                    const Split3 s0 = split2(u0, u1);
                    const Split3 s1 = split2(u2, u3);
                    const Split3 s2 = split2(u4, u5);
                    const Split3 s3 = split2(u6, u7);
                    PackA A0, A1, A2;
                    A0.u[0] = s0.d0; A0.u[1] = s1.d0; A0.u[2] = s2.d0; A0.u[3] = s3.d0;
                    A1.u[0] = s0.d1; A1.u[1] = s1.d1; A1.u[2] = s2.d1; A1.u[3] = s3.d1;
                    A2.u[0] = s0.d2; A2.u[1] = s1.d2; A2.u[2] = s2.d2; A2.u[3] = s3.d2;
                    #pragma unroll
                    for (int i = 0; i < 4; ++i) {
                        f32x4 a = acc[q][i];
                        a = __builtin_amdgcn_mfma_f32_16x16x32_bf16(A2.s, Bf[i][0], a, 0, 0, 0);
                        a = __builtin_amdgcn_mfma_f32_16x16x32_bf16(A1.s, Bf[i][1], a, 0, 0, 0);
                        a = __builtin_amdgcn_mfma_f32_16x16x32_bf16(A0.s, Bf[i][2], a, 0, 0, 0);
                        a = __builtin_amdgcn_mfma_f32_16x16x32_bf16(A1.s, Bf[i][0], a, 0, 0, 0);
                        a = __builtin_amdgcn_mfma_f32_16x16x32_bf16(A0.s, Bf[i][1], a, 0, 0, 0);
                        a = __builtin_amdgcn_mfma_f32_16x16x32_bf16(A0.s, Bf[i][0], a, 0, 0, 0);
                        acc[q][i] = a;
                    }
                }
            }
        }
    }

    // ---- readout: relu(acc+b2), per-row node mask, shfl-reduce, store ----
    float b2v[2][4];
    #pragma unroll
    for (int t = 0; t < 2; ++t)
        #pragma unroll
        for (int i = 0; i < 4; ++i)
            b2v[t][i] = b2[t*HH + (wave*4 + i)*16 + (lane & 15)];

    float p0[4], p1[4];
    #pragma unroll
    for (int i = 0; i < 4; ++i) { p0[i] = 0.f; p1[i] = 0.f; }
    #pragma unroll
    for (int q = 0; q < TMAX; ++q) {
        if (q < tiles) {
            const bool secB = (q >= tAt);
            int gv[4];
            #pragma unroll
            for (int rr = 0; rr < 4; ++rr)
                gv[rr] = rowinfo[q*16 + (lane >> 4)*4 + rr] >> 8;
            #pragma unroll
            for (int i = 0; i < 4; ++i) {
                const float bias = secB ? b2v[1][i] : b2v[0][i];
                #pragma unroll
                for (int rr = 0; rr < 4; ++rr) {
                    const float v = fmaxf(acc[q][i][rr] + bias, 0.f);
                    const bool valid = gv[rr] < 4;
                    p0[i] += (valid && !(gv[rr] & 1)) ? v : 0.f;
                    p1[i] += (valid &&  (gv[rr] & 1)) ? v : 0.f;
                }
            }
        }
    }
    #pragma unroll
    for (int i = 0; i < 4; ++i) {
        float v0 = p0[i], v1 = p1[i];
        v0 += __shfl_xor(v0, 16); v0 += __shfl_xor(v0, 32);
        v1 += __shfl_xor(v1, 16); v1 += __shfl_xor(v1, 32);
        if ((lane >> 4) == 0) {
            node_msg[((size_t)(b*NN + n0  ))*HH + (wave*4 + i)*16 + lane] = v0;
            node_msg[((size_t)(b*NN + n0+1))*HH + (wave*4 + i)*16 + lane] = v1;
        }
    }
}

// ---------------------------------------------------------------------------
// Decoder: unchanged from R8 (fused next-step PQ production).
// ---------------------------------------------------------------------------
__global__ __launch_bounds__(256, 2) void k_dec(
    float* __restrict__ state,
    const float* __restrict__ node_msg,
    const float* __restrict__ W1, const float* __restrict__ b1,   // (272,256)
    const float* __restrict__ W2, const float* __restrict__ b2,   // (256,256)
    const float* __restrict__ W3, const float* __restrict__ b3,   // (256,16)
    const float* __restrict__ eW1T,  // (2,256,32)
    const float* __restrict__ eb1,   // (2,256)
    float* __restrict__ PQ,
    float* __restrict__ out, int step)
{
    const int b    = blockIdx.x / 12;
    const int row0 = (blockIdx.x % 12) * 4;
    const int c    = threadIdx.x;    // 0..255

    __shared__ float in_s[4][272];
    __shared__ float d1s[4][HH];
    __shared__ float stn[4][DD];

    for (int i = c; i < 4*272; i += 256) {
        const int m = i / 272, k = i % 272;
        const int r = row0 + m;
        in_s[m][k] = (k < DD)
            ? state[((size_t)b*NN + r)*DD + k]
            : node_msg[((size_t)b*NN + r)*HH + (k - DD)];
    }
    __syncthreads();

    float a0[4];
    {
        const float bb = b1[c];
        #pragma unroll
        for (int m = 0; m < 4; ++m) a0[m] = bb;
        #pragma unroll 2
        for (int k4 = 0; k4 < 68; ++k4) {
            const float* wr = W1 + (k4*4)*HH;
            const float w0=wr[c], w1_=wr[HH+c], w2_=wr[2*HH+c], w3=wr[3*HH+c];
            #pragma unroll
            for (int m = 0; m < 4; ++m) {
                const float4 h = *(const float4*)&in_s[m][k4*4];
                a0[m] = fmaf(h.x,w0, fmaf(h.y,w1_, fmaf(h.z,w2_, fmaf(h.w,w3, a0[m]))));
            }
        }
        #pragma unroll
        for (int m = 0; m < 4; ++m) d1s[m][c] = fmaxf(a0[m], 0.f);
    }
    __syncthreads();
    {
        const float bb = b2[c];
        #pragma unroll
        for (int m = 0; m < 4; ++m) a0[m] = bb;
        #pragma unroll 2
        for (int k4 = 0; k4 < 64; ++k4) {
            const float* wr = W2 + (k4*4)*HH;
            const float w0=wr[c], w1_=wr[HH+c], w2_=wr[2*HH+c], w3=wr[3*HH+c];
            #pragma unroll
            for (int m = 0; m < 4; ++m) {
                const float4 h = *(const float4*)&d1s[m][k4*4];
                a0[m] = fmaf(h.x,w0, fmaf(h.y,w1_, fmaf(h.z,w2_, fmaf(h.w,w3, a0[m]))));
            }
        }
        __syncthreads();
        #pragma unroll
        for (int m = 0; m < 4; ++m) in_s[m][c] = fmaxf(a0[m], 0.f);
    }
    __syncthreads();
    if (c < 64) {
        const int m = c >> 4, cc = c & 15;
        float a = b3[cc];
        #pragma unroll 4
        for (int k4 = 0; k4 < 64; ++k4) {
            const float4 h = *(const float4*)&in_s[m][k4*4];
            a += h.x*W3[(k4*4+0)*16+cc] + h.y*W3[(k4*4+1)*16+cc]
               + h.z*W3[(k4*4+2)*16+cc] + h.w*W3[(k4*4+3)*16+cc];
        }
        const int r = row0 + m;
        const float v = state[((size_t)b*NN + r)*DD + cc] + a;
        state[((size_t)b*NN + r)*DD + cc] = v;
        out[(((size_t)b*NPRED + step)*NN + r)*DD + cc] = v;
        stn[m][cc] = v;
    }
    __syncthreads();
    float4 sm[4][4];
    #pragma unroll
    for (int m = 0; m < 4; ++m)
        #pragma unroll
        for (int f4 = 0; f4 < 4; ++f4)
            sm[m][f4] = *(const float4*)&stn[m][f4*4];
    #pragma unroll
    for (int k = 0; k < 4; ++k) {
        const int combo = c + 256*k;
        const int cc = combo & 255;
        const int pq = (combo >> 8) & 1;
        const int t  = combo >> 9;
        const float* wc = eW1T + ((size_t)t*HH + cc)*32 + pq*16;
        float4 w[4];
        #pragma unroll
        for (int f4 = 0; f4 < 4; ++f4) w[f4] = ((const float4*)wc)[f4];
        const float bias = pq ? eb1[t*HH + cc] : 0.f;
        #pragma unroll
        for (int m = 0; m < 4; ++m) {
            float v = bias;
            #pragma unroll
            for (int f4 = 0; f4 < 4; ++f4) {
                const float4 s = sm[m][f4];
                v = fmaf(s.x,w[f4].x, fmaf(s.y,w[f4].y, fmaf(s.z,w[f4].z, fmaf(s.w,w[f4].w, v))));
            }
            PQ[(size_t)(b*NN + row0 + m)*1024 + t*512 + pq*256 + cc] = v;
        }
    }
}

// ---------------------------------------------------------------------------
extern "C" void kernel_launch(void* const* d_in, const int* in_sizes, int n_in,
                              void* d_out, int out_size, void* d_ws, size_t ws_size,
                              hipStream_t stream)
{
    const float* time_segs  = (const float*)d_in[0];
    const float* edge_types = (const float*)d_in[1];
    const float* enc_W1 = (const float*)d_in[4];
    const float* enc_b1 = (const float*)d_in[5];
    const float* enc_W2 = (const float*)d_in[6];
    const float* enc_b2 = (const float*)d_in[7];
    const float* dec_W1 = (const float*)d_in[8];
    const float* dec_b1 = (const float*)d_in[9];
    const float* dec_W2 = (const float*)d_in[10];
    const float* dec_b2 = (const float*)d_in[11];
    const float* out_W  = (const float*)d_in[12];
    const float* out_b  = (const float*)d_in[13];
    float* out = (float*)d_out;

    float* state    = (float*)d_ws;                    // 24576 f
    float* node_msg = state + BB*NN*DD;                // 393216 f
    float* W1T      = node_msg + BB*NN*HH;             // 16384 f
    unsigned short* W2f = (unsigned short*)(W1T + 2*HH*32);   // 393216 us
    int*   lists    = (int*)(W2f + 2*3*65536);         // 86016 i
    int*   counts   = lists + BB*NN*LSTR;              // 3072 i
    float* PQ       = (float*)(counts + BB*NN*2);      // 1572864 f

    k_setup<<<192, 256, 0, stream>>>(time_segs, edge_types, enc_W1, enc_W2,
                                     enc_b1, state, W1T, W2f, PQ, lists, counts);
    for (int stp = 0; stp < NPRED; ++stp) {
        k_enc<<<BB*(NN/2), 256, 0, stream>>>(lists, counts, PQ, W2f,
                                             enc_b2, node_msg);
        k_dec<<<BB*12, 256, 0, stream>>>(state, node_msg,
                                         dec_W1, dec_b1, dec_W2, dec_b2,
                                         out_W, out_b, W1T, enc_b1, PQ, out, stp);
    }
}